// Round 1
// baseline (129.656 us; speedup 1.0000x reference)
//
#include <hip/hip_runtime.h>
#include <hip/hip_bf16.h>

// Problem: Gauss linking integral between kinematic-chain segment pairs.
// motion1, motion2: (B=32, F=1024, J=22, 3) fp32.
// 16 segments per motion (5 paths: 3,3,4,3,3 segments).
// gli[b,f,pp] = sum over segment pairs of path-pair pp of gauss integral.
// out[b,f] = max_pp |gli[b,f+1,pp] - gli[b,f,pp]|, shape (32, 1023).

#define NFRAMES 1024
#define NBATCH  32

__constant__ int c_seg_a[16] = {2,5,8,  1,4,7,  3,6,9,12,  14,17,19,  13,16,18};
__constant__ int c_seg_b[16] = {5,8,11, 4,7,10, 6,9,12,15, 17,19,21,  16,18,20};
__constant__ int c_seg_p[16] = {0,0,0,  1,1,1,  2,2,2,2,   3,3,3,     4,4,4};

struct V3 { float x, y, z; };

__device__ __forceinline__ V3 vsub(V3 a, V3 b) { return {a.x-b.x, a.y-b.y, a.z-b.z}; }
__device__ __forceinline__ V3 vcross(V3 a, V3 b) {
    return {a.y*b.z - a.z*b.y, a.z*b.x - a.x*b.z, a.x*b.y - a.y*b.x};
}
__device__ __forceinline__ float vdot(V3 a, V3 b) { return a.x*b.x + a.y*b.y + a.z*b.z; }

__device__ __forceinline__ V3 vnormalize(V3 v) {
    float n2 = v.x*v.x + v.y*v.y + v.z*v.z;
    float inv = (n2 > 0.0f) ? (1.0f / sqrtf(n2)) : 0.0f;   // matches ref: 0 when norm==0
    return {v.x*inv, v.y*inv, v.z*inv};
}

// One block = one (b,f) cell. 256 threads = 16x16 segment pairs.
__global__ __launch_bounds__(256)
void gli_kernel(const float* __restrict__ m1, const float* __restrict__ m2,
                float* __restrict__ gli)
{
    __shared__ float j1[66];   // 22 joints x 3
    __shared__ float j2[66];
    __shared__ float sums[25];

    const int bf = blockIdx.x;
    const int t  = threadIdx.x;
    const size_t base = (size_t)bf * 66;

    if (t < 66)       j1[t]      = m1[base + t];
    else if (t < 132) j2[t - 66] = m2[base + (t - 66)];
    if (t < 25) sums[t] = 0.0f;
    __syncthreads();

    const int i1 = t >> 4;    // motion1 segment index
    const int i2 = t & 15;    // motion2 segment index

    const int a1 = c_seg_a[i1] * 3, b1 = c_seg_b[i1] * 3;
    const int a2 = c_seg_a[i2] * 3, b2 = c_seg_b[i2] * 3;

    V3 S1{j1[a1], j1[a1+1], j1[a1+2]};
    V3 E1{j1[b1], j1[b1+1], j1[b1+2]};
    V3 S2{j2[a2], j2[a2+1], j2[a2+2]};
    V3 E2{j2[b2], j2[b2+1], j2[b2+2]};

    V3 r13 = vsub(S2, S1);
    V3 r14 = vsub(E2, S1);
    V3 r23 = vsub(S2, E1);
    V3 r24 = vsub(E2, E1);
    V3 r12 = vsub(E1, S1);
    V3 r34 = vsub(E2, S2);

    V3 f0 = vnormalize(vcross(r13, r14));
    V3 f1 = vnormalize(vcross(r14, r24));
    V3 f2 = vnormalize(vcross(r24, r23));
    V3 f3 = vnormalize(vcross(r23, r13));

    const float lo = -1.0f + 1e-7f, hi = 1.0f - 1e-7f;
    float d0 = fminf(fmaxf(vdot(f0, f1), lo), hi);
    float d1 = fminf(fmaxf(vdot(f1, f2), lo), hi);
    float d2 = fminf(fmaxf(vdot(f2, f3), lo), hi);
    float d3 = fminf(fmaxf(vdot(f3, f0), lo), hi);

    float g = asinf(d0) + asinf(d1) + asinf(d2) + asinf(d3);

    float sgn = vdot(vcross(r34, r12), r13);
    g = (sgn <= 0.0f) ? -g : g;
    g *= 0.07957747154594767f;  // 1/(4*pi)

    atomicAdd(&sums[c_seg_p[i1] * 5 + c_seg_p[i2]], g);
    __syncthreads();

    if (t < 25) gli[(size_t)bf * 25 + t] = sums[t];
}

// out[b,f] = max_p |gli[b,f+1,p] - gli[b,f,p]|
__global__ __launch_bounds__(256)
void vel_kernel(const float* __restrict__ gli, float* __restrict__ out)
{
    const int f = blockIdx.x * blockDim.x + threadIdx.x;
    const int b = blockIdx.y;
    if (f >= NFRAMES - 1) return;

    const float* p0 = gli + ((size_t)b * NFRAMES + f) * 25;
    float m = 0.0f;   // |diff| >= 0, so 0 is a safe identity
#pragma unroll
    for (int p = 0; p < 25; ++p)
        m = fmaxf(m, fabsf(p0[p + 25] - p0[p]));
    out[(size_t)b * (NFRAMES - 1) + f] = m;
}

extern "C" void kernel_launch(void* const* d_in, const int* in_sizes, int n_in,
                              void* d_out, int out_size, void* d_ws, size_t ws_size,
                              hipStream_t stream)
{
    const float* m1 = (const float*)d_in[0];
    const float* m2 = (const float*)d_in[1];
    float* out = (float*)d_out;
    float* gli = (float*)d_ws;   // needs 32*1024*25*4 = 3.3 MB

    hipLaunchKernelGGL(gli_kernel, dim3(NBATCH * NFRAMES), dim3(256), 0, stream,
                       m1, m2, gli);
    hipLaunchKernelGGL(vel_kernel, dim3((NFRAMES - 1 + 255) / 256, NBATCH), dim3(256),
                       0, stream, gli, out);
}